// Round 15
// baseline (1187.083 us; speedup 1.0000x reference)
//
#include <hip/hip_runtime.h>
#include <math.h>

#define LOG0f (-1.0e30f)
#define ACTIVE_TH (-1.0e29f)
#define PRUNE_TH (-9.0f)
#define VCAB 128
#define HSZ 4096
#define HMASK (HSZ - 1)
#define MAXN 2052
#define HEMPTY 0xFFFFFFFFu

// JAX-exact logaddexp: max + log1p(exp(-|a-b|)) in f32
__device__ __forceinline__ float lae(float a, float b) {
    float mx = fmaxf(a, b);
    float d = fabsf(a - b);
    return mx + log1pf(expf(-d));
}
// monotonic float->uint transform (order-preserving; >0 for all finite floats)
__device__ __forceinline__ unsigned mono(float f) {
    unsigned u = __float_as_uint(f);
    return (u & 0x80000000u) ? ~u : (u | 0x80000000u);
}
__device__ __forceinline__ float mono_inv(unsigned m) {
    unsigned u = (m & 0x80000000u) ? (m & 0x7FFFFFFFu) : ~m;
    return __uint_as_float(u);
}
__device__ __forceinline__ unsigned rlaneu(unsigned x, int l) {
    return (unsigned)__builtin_amdgcn_readlane((int)x, l);
}
__device__ __forceinline__ float rlanef(float x, int l) {
    return __uint_as_float(rlaneu(__float_as_uint(x), l));
}

// wave-wide max of u32: DPP up-sweep into lane 63 (rocPRIM gfx9 ladder), readlane -> uniform
__device__ __forceinline__ unsigned wred_max_u32(unsigned x) {
    unsigned y;
    y = (unsigned)__builtin_amdgcn_update_dpp(0, (int)x, 0x111, 0xf, 0xf, false);  // row_shr:1
    x = (y > x) ? y : x;
    y = (unsigned)__builtin_amdgcn_update_dpp(0, (int)x, 0x112, 0xf, 0xf, false);  // row_shr:2
    x = (y > x) ? y : x;
    y = (unsigned)__builtin_amdgcn_update_dpp(0, (int)x, 0x114, 0xf, 0xf, false);  // row_shr:4
    x = (y > x) ? y : x;
    y = (unsigned)__builtin_amdgcn_update_dpp(0, (int)x, 0x118, 0xf, 0xf, false);  // row_shr:8
    x = (y > x) ? y : x;
    y = (unsigned)__builtin_amdgcn_update_dpp(0, (int)x, 0x142, 0xa, 0xf, false);  // row_bcast:15
    x = (y > x) ? y : x;
    y = (unsigned)__builtin_amdgcn_update_dpp(0, (int)x, 0x143, 0xc, 0xf, false);  // row_bcast:31
    x = (y > x) ? y : x;
    return (unsigned)__builtin_amdgcn_readlane((int)x, 63);
}

#define REP8(X) X(0) X(1) X(2) X(3) X(4) X(5) X(6) X(7)
// depth-3 binary-tree select of named scalars n_0..n_7 by runtime s in [0,8)
#define TSEL8(out, s, n)                                                        \
    do {                                                                        \
        __typeof__(n##_0) e0_ = ((s) & 1u) ? n##_1 : n##_0;                     \
        __typeof__(n##_0) e1_ = ((s) & 1u) ? n##_3 : n##_2;                     \
        __typeof__(n##_0) e2_ = ((s) & 1u) ? n##_5 : n##_4;                     \
        __typeof__(n##_0) e3_ = ((s) & 1u) ? n##_7 : n##_6;                     \
        __typeof__(n##_0) f0_ = ((s) & 2u) ? e1_ : e0_;                         \
        __typeof__(n##_0) f1_ = ((s) & 2u) ? e3_ : e2_;                         \
        out = ((s) & 4u) ? f1_ : f0_;                                           \
    } while (0)

__global__ __launch_bounds__(64)
void ctc_beam_kernel(const float* __restrict__ probs, const int* __restrict__ lengths,
                     const int* __restrict__ blank_p, int* __restrict__ out_seq,
                     int* __restrict__ out_len, int T) {
    __shared__ unsigned hsh[HSZ];        // dedup map (parent,label)->node: (hkey<<12)|id
    __shared__ unsigned nodeinfo[MAXN];  // (parent<<7)|label per node id
    __shared__ int sh_seq[256];

    const int lane = threadIdx.x;
    const int b = blockIdx.x;
    const int blank = blank_p[0];
    const int length = lengths[b];
    const float* __restrict__ P = probs + (size_t)b * T * VCAB;
    const float4* __restrict__ P4 = (const float4*)P;
    const int own = lane & 7;     // beam owned by this lane
    const int slice = lane >> 3;  // vocab slice [slice*16, +16)
    const int vbase = slice * 16;
    // ext tie-break word for slot k: cl = KLB - k  (== ~refidx); cont: ~own
    const unsigned KLB = ~(8u + (unsigned)(own * VCAB + vbase));

    for (int i = lane; i < HSZ; i += 64) hsh[i] = HEMPTY;
    __syncthreads();

    // packed wave-uniform metadata as NAMED scalars: A=(node<<12)|par, B=(len<<7)|last
    unsigned A8_0, A8_1, A8_2, A8_3, A8_4, A8_5, A8_6, A8_7;
    unsigned B8_0, B8_1, B8_2, B8_3, B8_4, B8_5, B8_6, B8_7;
#define INIT(j) A8_##j = 0xFFFu; B8_##j = (unsigned)blank;
    REP8(INIT)
#undef INIT
    // per-lane own-beam state (lane j authoritative for beam j; others replicas)
    float pb_own = (own == 0) ? 0.0f : LOG0f;  // root: blank prob = log(1)
    float pnb_own = LOG0f;
    int len_own = 0, last_own = blank;
    unsigned node_own = 0, par_own = 0xFFFu;

    // distance-1 prefetch; prB pipelined
    float4 s0, s1, s2, s3;
    float prL, prH, prB;
    {
        int base4 = (vbase >> 2);
        s0 = P4[base4]; s1 = P4[base4 + 1]; s2 = P4[base4 + 2]; s3 = P4[base4 + 3];
        prL = P[lane]; prH = P[64 + lane];
        prB = (blank < 64) ? rlanef(prL, blank) : rlanef(prH, blank - 64);
    }

#pragma clang loop unroll(disable)
    for (int t = 0; t < length; ++t) {
        // early cross-lane issue: row prob at own's last label (latency hidden below)
        float sfL = __shfl(prL, last_own & 63, 64);
        float sfH = __shfl(prH, last_own & 63, 64);
        // branchless clamped prefetch of row t+1
        const int tn = (t + 1 < length) ? (t + 1) : (length - 1);
        float4 n0, n1, n2, n3;
        float nprL, nprH;
        {
            int base4 = tn * 32 + (vbase >> 2);
            n0 = P4[base4]; n1 = P4[base4 + 1]; n2 = P4[base4 + 2]; n3 = P4[base4 + 3];
            nprL = P[(size_t)tn * VCAB + lane];
            nprH = P[(size_t)tn * VCAB + 64 + lane];
        }

        float pt_own = lae(pb_own, pnb_own);
        unsigned long long bal = __ballot(pt_own > ACTIVE_TH);
        unsigned actmask = (unsigned)bal & 0xFFu;
        bool act_own = (actmask >> own) & 1u;

        // uniform per-beam prob tables (for parent values)
#define TBL(j) float pb8_##j = rlanef(pb_own, j); float pt8_##j = rlanef(pt_own, j);
        REP8(TBL)
#undef TBL

        // own parent match by node-id identity; at most one active j matches
        bool gate = act_own && (len_own > 0);
#define PMB(j) bool pm##j = gate && ((actmask >> j) & 1u) && ((A8_##j >> 12) == par_own);
        REP8(PMB)
#undef PMB
        bool matched = (pm0 | pm1) | (pm2 | pm3) | ((pm4 | pm5) | (pm6 | pm7));
        unsigned p_own = ((pm1 ? 1u : 0u) | (pm2 ? 2u : 0u)) |
                         ((pm3 ? 3u : 0u) | (pm4 ? 4u : 0u)) |
                         (((pm5 ? 5u : 0u) | (pm6 ? 6u : 0u)) | (pm7 ? 7u : 0u));
        float pbp, ptp;
        unsigned Bp;
        TSEL8(pbp, p_own, pb8);
        TSEL8(ptp, p_own, pt8);
        TSEL8(Bp, p_own, B8);
        int lastp = (int)(Bp & 127u);
        float pprev = matched ? ((last_own == lastp) ? pbp : ptp) : LOG0f;
        float prLast = (last_own < 64) ? sfL : sfH;

        float contb_own = pt_own + prB;
        float contnb_own = (len_own > 0) ? (lae(pnb_own, pprev) + prLast) : LOG0f;
        float tot_own = lae(contb_own, contnb_own);

        // labels in my slice claimed as existing children of my beam (OR-tree)
#define CLM(j)                                                                  \
        unsigned c16_##j;                                                       \
        {                                                                       \
            unsigned lastj = B8_##j & 127u;                                     \
            bool mj = ((actmask >> j) & 1u) && act_own &&                       \
                      (node_own == (A8_##j & 0xFFFu));                          \
            bool ins = ((lastj >> 4) == (unsigned)slice);                       \
            c16_##j = (mj && ins) ? (1u << (lastj & 15u)) : 0u;                 \
        }
        REP8(CLM)
#undef CLM
        unsigned claimed16 = ((c16_0 | c16_1) | (c16_2 | c16_3)) |
                             ((c16_4 | c16_5) | (c16_6 | c16_7));

        // candidate value-words (named); full key = (kh, cl), cl: ext k -> KLB-k; cont -> ~own
        unsigned kh_0, kh_1, kh_2, kh_3, kh_4, kh_5, kh_6, kh_7, kh_8, kh_9,
                 kh_10, kh_11, kh_12, kh_13, kh_14, kh_15, kh_16;
#define MAKEK(c, pv)                                                                     \
        {                                                                                \
            int v = vbase + (c);                                                         \
            float prev = (v == last_own) ? pb_own : pt_own;                              \
            float val = (pv) + prev;                                                     \
            bool bad = (v == blank) | ((pv) <= PRUNE_TH) | (!act_own) |                  \
                       (bool)((claimed16 >> (c)) & 1u);                                  \
            if (bad) val = LOG0f;                                                        \
            kh_##c = mono(val);                                                          \
        }
        MAKEK(0, s0.x) MAKEK(1, s0.y) MAKEK(2, s0.z) MAKEK(3, s0.w)
        MAKEK(4, s1.x) MAKEK(5, s1.y) MAKEK(6, s1.z) MAKEK(7, s1.w)
        MAKEK(8, s2.x) MAKEK(9, s2.y) MAKEK(10, s2.z) MAKEK(11, s2.w)
        MAKEK(12, s3.x) MAKEK(13, s3.y) MAKEK(14, s3.z) MAKEK(15, s3.w)
#undef MAKEK
        kh_16 = (lane < 8) ? mono(tot_own) : 0u;

        // per-lane top-3 cache as (value, rank); rank 0=cont, k+1=ext slot k.
        // FOUR parallel insert chains (ascending rank) + 2-level exact merge tree.
#define CINS(c1v, c1p, c2v, c2p, c3v, c3p, V, PR)                               \
        {                                                                       \
            unsigned v_ = (V); bool g1 = v_ > c1v, g2 = v_ > c2v, g3 = v_ > c3v; \
            unsigned x1v = g1 ? v_ : c1v;  unsigned x1p = g1 ? (PR) : c1p;      \
            unsigned x2v = g1 ? c1v : (g2 ? v_ : c2v);                          \
            unsigned x2p = g1 ? c1p : (g2 ? (PR) : c2p);                        \
            c3v = (g1 | g2) ? c2v : (g3 ? v_ : c3v);                            \
            c3p = (g1 | g2) ? c2p : (g3 ? (PR) : c3p);                          \
            c1v = x1v; c1p = x1p; c2v = x2v; c2p = x2p;                         \
        }
        unsigned a1v = 0u, a1p = 31u, a2v = 0u, a2p = 31u, a3v = 0u, a3p = 31u;
        unsigned b1v = 0u, b1p = 31u, b2v = 0u, b2p = 31u, b3v = 0u, b3p = 31u;
        unsigned c1v = 0u, c1p = 31u, c2v = 0u, c2p = 31u, c3v = 0u, c3p = 31u;
        unsigned d1v = 0u, d1p = 31u, d2v = 0u, d2p = 31u, d3v = 0u, d3p = 31u;
        CINS(a1v, a1p, a2v, a2p, a3v, a3p, kh_16, 0u)
        CINS(a1v, a1p, a2v, a2p, a3v, a3p, kh_0, 1u)
        CINS(a1v, a1p, a2v, a2p, a3v, a3p, kh_4, 5u)
        CINS(a1v, a1p, a2v, a2p, a3v, a3p, kh_8, 9u)
        CINS(a1v, a1p, a2v, a2p, a3v, a3p, kh_12, 13u)
        CINS(b1v, b1p, b2v, b2p, b3v, b3p, kh_1, 2u)
        CINS(b1v, b1p, b2v, b2p, b3v, b3p, kh_5, 6u)
        CINS(b1v, b1p, b2v, b2p, b3v, b3p, kh_9, 10u)
        CINS(b1v, b1p, b2v, b2p, b3v, b3p, kh_13, 14u)
        CINS(c1v, c1p, c2v, c2p, c3v, c3p, kh_2, 3u)
        CINS(c1v, c1p, c2v, c2p, c3v, c3p, kh_6, 7u)
        CINS(c1v, c1p, c2v, c2p, c3v, c3p, kh_10, 11u)
        CINS(c1v, c1p, c2v, c2p, c3v, c3p, kh_14, 15u)
        CINS(d1v, d1p, d2v, d2p, d3v, d3p, kh_3, 4u)
        CINS(d1v, d1p, d2v, d2p, d3v, d3p, kh_7, 8u)
        CINS(d1v, d1p, d2v, d2p, d3v, d3p, kh_11, 12u)
        CINS(d1v, d1p, d2v, d2p, d3v, d3p, kh_15, 16u)
#undef CINS
#define GTE(xv, xp, yv, yp) (((xv) > (yv)) || ((xv) == (yv) && (xp) < (yp)))
        // exact merge of two sorted (val,rank) triples -> top-3 (proven in v12/v13)
#define MRG3(o1v, o1p, o2v, o2p, o3v, o3p, x1v, x1p, x2v, x2p, x3v, x3p,        \
             y1v, y1p, y2v, y2p, y3v, y3p)                                      \
        {                                                                       \
            bool gA = GTE(x1v, x1p, y1v, y1p);                                  \
            o1v = gA ? x1v : y1v; o1p = gA ? x1p : y1p;                         \
            unsigned uv = gA ? y1v : x1v, up = gA ? y1p : x1p;                  \
            bool gS = GTE(x2v, x2p, y2v, y2p);                                  \
            unsigned vv = gS ? x2v : y2v, vp = gS ? x2p : y2p;                  \
            unsigned wv = gS ? y2v : x2v, wp = gS ? y2p : x2p;                  \
            bool gM = GTE(uv, up, vv, vp);                                      \
            o2v = gM ? uv : vv; o2p = gM ? up : vp;                             \
            unsigned mnv = gM ? vv : uv, mnp = gM ? vp : up;                    \
            bool gX = GTE(x2v, x2p, y1v, y1p);                                  \
            bool gY = GTE(y2v, y2p, x1v, x1p);                                  \
            unsigned Xv = gX ? x3v : (gY ? y3v : 0u);                           \
            unsigned Xp = gX ? x3p : (gY ? y3p : 31u);                          \
            bool gW = GTE(wv, wp, Xv, Xp);                                      \
            unsigned Yv = gW ? wv : Xv, Yp = gW ? wp : Xp;                      \
            bool gF = GTE(mnv, mnp, Yv, Yp);                                    \
            o3v = gF ? mnv : Yv; o3p = gF ? mnp : Yp;                           \
        }
        unsigned p1v, p1p, p2v, p2p, p3v, p3p, q1v, q1p, q2v, q2p, q3v, q3p;
        MRG3(p1v, p1p, p2v, p2p, p3v, p3p,
             a1v, a1p, a2v, a2p, a3v, a3p, b1v, b1p, b2v, b2p, b3v, b3p)
        MRG3(q1v, q1p, q2v, q2p, q3v, q3p,
             c1v, c1p, c2v, c2p, c3v, c3p, d1v, d1p, d2v, d2p, d3v, d3p)
        unsigned m1v, m1p, m2v, m2p, m3v, m3p;
        MRG3(m1v, m1p, m2v, m2p, m3v, m3p,
             p1v, p1p, p2v, p2p, p3v, p3p, q1v, q1p, q2v, q2p, q3v, q3p)
#undef MRG3
#undef GTE

        // continuation-value tables BEFORE rounds (latency hidden under rounds)
#define CBT(j) float cb8_##j = rlanef(contb_own, j); float cn8_##j = rlanef(contnb_own, j);
        REP8(CBT)
#undef CBT

        // top-8 extraction: submit-always, shift-on-win, refill on underflow.
        unsigned myM = 0u, myL = 0u;
#define RS1(k)                                                                  \
        {                                                                       \
            unsigned kv = kh_##k; unsigned kcl = KLB - (unsigned)(k);           \
            bool below = (kv < M) | ((kv == M) & (kcl < L));                    \
            bool bet = below & ((kv > bv) | ((kv == bv) & (kcl > bcl)));        \
            bv = bet ? kv : bv; bp = bet ? (unsigned)((k) + 1) : bp;            \
            bcl = bet ? kcl : bcl;                                              \
        }
#define ROUND(r)                                                                \
        do {                                                                    \
            unsigned ch = m1v;                                                  \
            unsigned cl = (m1p == 0u) ? ~(unsigned)own : (KLB - (m1p - 1u));    \
            unsigned M = wred_max_u32(ch);                                      \
            unsigned long long tb = __ballot(ch == M);                          \
            unsigned L;                                                         \
            if (__builtin_popcountll(tb) == 1) {                                \
                L = rlaneu(cl, __builtin_ctzll(tb));                            \
            } else {                                                            \
                unsigned lo2 = (ch == M) ? cl : 0u;                             \
                L = wred_max_u32(lo2);                                          \
            }                                                                   \
            bool mine = (own == (r));                                           \
            myM = mine ? M : myM;                                               \
            myL = mine ? L : myL;                                               \
            bool won = (ch == M) & (cl == L);                                   \
            m1v = won ? m2v : m1v; m1p = won ? m2p : m1p;                       \
            m2v = won ? m3v : m2v; m2p = won ? m3p : m2p;                       \
            m3v = won ? 0u : m3v;  m3p = won ? 31u : m3p;                       \
            bool under = won & (m1v == 0u);                                     \
            if (__any(under)) {                                                 \
                if (under) {  /* rescan: best key strictly below (M,L) */       \
                    unsigned bv = 0u, bp = 31u, bcl = 0u;                       \
                    RS1(0) RS1(1) RS1(2) RS1(3) RS1(4) RS1(5) RS1(6) RS1(7)     \
                    RS1(8) RS1(9) RS1(10) RS1(11) RS1(12) RS1(13) RS1(14)       \
                    RS1(15)                                                     \
                    {                                                           \
                        unsigned kv = kh_16; unsigned kcl = ~(unsigned)own;     \
                        bool below = (kv < M) | ((kv == M) & (kcl < L));        \
                        bool bet = below &                                      \
                                   ((kv > bv) | ((kv == bv) & (kcl > bcl)));    \
                        bv = bet ? kv : bv; bp = bet ? 0u : bp;                 \
                        bcl = bet ? kcl : bcl;                                  \
                    }                                                           \
                    m1v = bv; m1p = bp;  /* bv==0 -> lane exhausted */          \
                }                                                               \
            }                                                                   \
        } while (0);
        ROUND(0) ROUND(1) ROUND(2) ROUND(3) ROUND(4) ROUND(5) ROUND(6) ROUND(7)
#undef ROUND
#undef RS1

        // per-lane decode of round `own` (lanes 8..63 = replicas of beam own)
        unsigned sel = ~myL;
        bool iscont = sel < 8u;
        unsigned e = sel - 8u;
        unsigned s = iscont ? sel : (e >> 7);
        unsigned lab = e & 127u;
        unsigned Asel, Bsel;
        TSEL8(Asel, s, A8);
        TSEL8(Bsel, s, B8);
        unsigned nd = Asel >> 12;
        unsigned ln = Bsel >> 7;
        float cbs, cns;
        TSEL8(cbs, s, cb8);
        TSEL8(cns, s, cn8);
        float npb_own = iscont ? cbs : LOG0f;
        float npnb_own = iscont ? cns : mono_inv(myM);  // ext pnb == sort value bitwise
        unsigned A_new = iscont ? Asel : nd;  // ext: node-field=0 (patched), par=nd
        unsigned B_new = iscont ? Bsel : (((ln + 1u) << 7) | lab);
        unsigned long long extbal = __ballot(!iscont);
        unsigned extmask = (unsigned)extbal & 0xFFu;  // bit r: round r was an extension

        // dedup-hash inserts: lane r handles new beam r (deterministic pre-ids)
        unsigned insRes = 0;
        if ((extmask >> lane) & 1u) {
            unsigned preid = 1u + 8u * (unsigned)t + (unsigned)lane;
            unsigned hkey = (nd << 7) | lab;
            unsigned entry = (hkey << 12) | preid;
            unsigned h = ((hkey * 2654435761u) >> 20) & HMASK;
            for (;;) {
                unsigned prev = atomicCAS(&hsh[h], HEMPTY, entry);
                if (prev == HEMPTY) { nodeinfo[preid] = hkey; insRes = preid; break; }
                if ((prev >> 12) == hkey) { insRes = prev & 0xFFFu; break; }
                h = (h + 1) & HMASK;
            }
        }
        // commit uniform metadata: gather from lane r; patch ext node ids
#define COMMIT(r)                                                               \
        {                                                                       \
            unsigned Ar = rlaneu(A_new, r);                                     \
            unsigned Br = rlaneu(B_new, r);                                     \
            if ((extmask >> (r)) & 1u)  /* uniform condition */                 \
                Ar = (rlaneu(insRes, (r)) << 12) | (Ar & 0xFFFu);               \
            A8_##r = Ar; B8_##r = Br;                                           \
        }
        REP8(COMMIT)
#undef COMMIT
        // own-state: node from committed uniform metadata (VALU tree select)
        unsigned Aown;
        TSEL8(Aown, (unsigned)own, A8);
        node_own = Aown >> 12;
        par_own = A_new & 0xFFFu;
        len_own = (int)(B_new >> 7);
        last_own = (int)(B_new & 127u);
        pb_own = npb_own; pnb_own = npnb_own;

        // rotate prefetch: cur <- next; prB for next step
        s0 = n0; s1 = n1; s2 = n2; s3 = n3;
        prL = nprL; prH = nprH;
        prB = (blank < 64) ? rlanef(prL, blank) : rlanef(prH, blank - 64);
    }

    // final argmax of totals (ties -> lowest index), then parent-walk reconstruction
    unsigned fh, fl;
    {
        float tot = lae(pb_own, pnb_own);
        fh = (lane < 8) ? mono(tot) : 0u;
        fl = (lane < 8) ? ~(unsigned)lane : 0u;
    }
    {
        unsigned M = wred_max_u32(fh);
        unsigned lo2 = (fh == M) ? fl : 0u;
        fl = wred_max_u32(lo2);
    }
    const unsigned best = ~fl;
    unsigned Ab, Bb;
    TSEL8(Ab, best, A8);
    TSEL8(Bb, best, B8);
    int L = (int)(Bb >> 7);
    unsigned c = Ab >> 12;
    if (lane == 0) {
        for (int k = L - 1; k >= 0; --k) {
            unsigned info = nodeinfo[c];
            sh_seq[k] = (int)(info & 127u);
            c = info >> 7;
        }
    }
    __syncthreads();
    for (int j = lane; j < T; j += 64)
        out_seq[(size_t)b * T + j] = (j < L) ? sh_seq[j] : 0;
    if (lane == 0) out_len[b] = L;
}

extern "C" void kernel_launch(void* const* d_in, const int* in_sizes, int n_in,
                              void* d_out, int out_size, void* d_ws, size_t ws_size,
                              hipStream_t stream) {
    const float* probs = (const float*)d_in[0];
    const int* lengths = (const int*)d_in[1];
    // d_in[2] = beam_width (fixed 8, compiled in); d_in[3] = blank_index
    const int* blank_p = (const int*)d_in[3];
    const int B = in_sizes[1];
    const int T = in_sizes[0] / (B * VCAB);
    int* out = (int*)d_out;
    ctc_beam_kernel<<<B, 64, 0, stream>>>(probs, lengths, blank_p, out,
                                          out + (size_t)B * T, T);
}

// Round 16
// 1130.413 us; speedup vs baseline: 1.0501x; 1.0501x over previous
//
#include <hip/hip_runtime.h>
#include <math.h>

#define LOG0f (-1.0e30f)
#define ACTIVE_TH (-1.0e29f)
#define PRUNE_TH (-9.0f)
#define VCAB 128
#define HSZ 4096
#define HMASK (HSZ - 1)
#define MAXN 2052
#define HEMPTY 0xFFFFFFFFu

// JAX-exact logaddexp: max + log1p(exp(-|a-b|)) in f32
__device__ __forceinline__ float lae(float a, float b) {
    float mx = fmaxf(a, b);
    float d = fabsf(a - b);
    return mx + log1pf(expf(-d));
}
// monotonic float->uint transform (order-preserving; >0 for all finite floats)
__device__ __forceinline__ unsigned mono(float f) {
    unsigned u = __float_as_uint(f);
    return (u & 0x80000000u) ? ~u : (u | 0x80000000u);
}
__device__ __forceinline__ float mono_inv(unsigned m) {
    unsigned u = (m & 0x80000000u) ? (m & 0x7FFFFFFFu) : ~m;
    return __uint_as_float(u);
}
__device__ __forceinline__ unsigned rlaneu(unsigned x, int l) {
    return (unsigned)__builtin_amdgcn_readlane((int)x, l);
}
__device__ __forceinline__ float rlanef(float x, int l) {
    return __uint_as_float(rlaneu(__float_as_uint(x), l));
}
// select a[s] from a statically-indexed 8-array (cndmask chain)
__device__ __forceinline__ unsigned sel8u(const unsigned a[8], unsigned s) {
    unsigned r = a[0];
#pragma unroll
    for (int j = 1; j < 8; ++j) r = (s == (unsigned)j) ? a[j] : r;
    return r;
}

// wave-wide max of u32, SPLIT form: 4 DPP row-max levels (row max lands in
// lanes 15/31/47/63) + 4 parallel readlanes + depth-2 scalar max tree.
// 2 fewer dependent DPP levels than the bcast ladder; tail on the SALU pipe.
__device__ __forceinline__ unsigned wred_max_u32(unsigned x) {
    unsigned y;
    y = (unsigned)__builtin_amdgcn_update_dpp(0, (int)x, 0x111, 0xf, 0xf, false);  // row_shr:1
    x = (y > x) ? y : x;
    y = (unsigned)__builtin_amdgcn_update_dpp(0, (int)x, 0x112, 0xf, 0xf, false);  // row_shr:2
    x = (y > x) ? y : x;
    y = (unsigned)__builtin_amdgcn_update_dpp(0, (int)x, 0x114, 0xf, 0xf, false);  // row_shr:4
    x = (y > x) ? y : x;
    y = (unsigned)__builtin_amdgcn_update_dpp(0, (int)x, 0x118, 0xf, 0xf, false);  // row_shr:8
    x = (y > x) ? y : x;  // lane 15 of each 16-row now holds that row's max
    unsigned r0 = rlaneu(x, 15);
    unsigned r1 = rlaneu(x, 31);
    unsigned r2 = rlaneu(x, 47);
    unsigned r3 = rlaneu(x, 63);
    unsigned m01 = (r0 > r1) ? r0 : r1;  // s_max_u32 (uniform operands)
    unsigned m23 = (r2 > r3) ? r2 : r3;
    return (m01 > m23) ? m01 : m23;
}

#define REP8(X) X(0) X(1) X(2) X(3) X(4) X(5) X(6) X(7)
#define REP7(X) X(1) X(2) X(3) X(4) X(5) X(6) X(7)
#define SEL8N(out, s, n)                                                        \
    do {                                                                        \
        out = n##_0;                                                            \
        out = ((s) == 1u) ? n##_1 : out; out = ((s) == 2u) ? n##_2 : out;       \
        out = ((s) == 3u) ? n##_3 : out; out = ((s) == 4u) ? n##_4 : out;       \
        out = ((s) == 5u) ? n##_5 : out; out = ((s) == 6u) ? n##_6 : out;       \
        out = ((s) == 7u) ? n##_7 : out;                                        \
    } while (0)

__global__ __launch_bounds__(64)
void ctc_beam_kernel(const float* __restrict__ probs, const int* __restrict__ lengths,
                     const int* __restrict__ blank_p, int* __restrict__ out_seq,
                     int* __restrict__ out_len, int T) {
    __shared__ unsigned hsh[HSZ];        // dedup map (parent,label)->node: (hkey<<12)|id
    __shared__ unsigned nodeinfo[MAXN];  // (parent<<7)|label per node id
    __shared__ int sh_seq[256];

    const int lane = threadIdx.x;
    const int b = blockIdx.x;
    const int blank = blank_p[0];
    const int length = lengths[b];
    const float* __restrict__ P = probs + (size_t)b * T * VCAB;
    const float4* __restrict__ P4 = (const float4*)P;
    const int own = lane & 7;     // beam owned by this lane
    const int slice = lane >> 3;  // vocab slice [slice*16, +16)
    const int vbase = slice * 16;
    // ext tie-break word for slot k: cl = KLB - k  (== ~refidx); cont: ~own
    const unsigned KLB = ~(8u + (unsigned)(own * VCAB + vbase));

    for (int i = lane; i < HSZ; i += 64) hsh[i] = HEMPTY;
    __syncthreads();

    // packed wave-uniform metadata: A8[j]=(node<<12)|par, B8[j]=(len<<7)|last
    unsigned A8[8], B8[8];
#pragma unroll
    for (int j = 0; j < 8; ++j) { A8[j] = 0xFFFu; B8[j] = (unsigned)blank; }
    // per-lane own-beam state (lane j authoritative for beam j; others replicas)
    float pb_own = (own == 0) ? 0.0f : LOG0f;  // root: blank prob = log(1)
    float pnb_own = LOG0f;
    int len_own = 0, last_own = blank;
    unsigned node_own = 0, par_own = 0xFFFu;

    // distance-2 prefetch: s* = row t, m* = row t+1; prB pipelined one step early
    float4 s0, s1, s2, s3, m0, m1_, m2_, m3_;
    float prL, prH, mprL, mprH, prB, mprB;
    {
        int base4 = (vbase >> 2);
        s0 = P4[base4]; s1 = P4[base4 + 1]; s2 = P4[base4 + 2]; s3 = P4[base4 + 3];
        prL = P[lane]; prH = P[64 + lane];
        int t1 = (1 < length) ? 1 : 0;
        int b1 = t1 * 32 + (vbase >> 2);
        m0 = P4[b1]; m1_ = P4[b1 + 1]; m2_ = P4[b1 + 2]; m3_ = P4[b1 + 3];
        mprL = P[(size_t)t1 * VCAB + lane];
        mprH = P[(size_t)t1 * VCAB + 64 + lane];
        prB = (blank < 64) ? rlanef(prL, blank) : rlanef(prH, blank - 64);
        mprB = (blank < 64) ? rlanef(mprL, blank) : rlanef(mprH, blank - 64);
    }

#pragma clang loop unroll(disable)
    for (int t = 0; t < length; ++t) {
        // early cross-lane issue: row prob at own's last label (latency hidden below)
        float sfL = __shfl(prL, last_own & 63, 64);
        float sfH = __shfl(prH, last_own & 63, 64);
        // issue loads for row t+2 (clamped)
        const int t2 = (t + 2 < length) ? (t + 2) : (length - 1);
        float4 q0, q1, q2, q3;
        float qprL, qprH;
        {
            int base4 = t2 * 32 + (vbase >> 2);
            q0 = P4[base4]; q1 = P4[base4 + 1]; q2 = P4[base4 + 2]; q3 = P4[base4 + 3];
            qprL = P[(size_t)t2 * VCAB + lane];
            qprH = P[(size_t)t2 * VCAB + 64 + lane];
        }

        float pt_own = lae(pb_own, pnb_own);
        unsigned long long bal = __ballot(pt_own > ACTIVE_TH);
        unsigned actmask = (unsigned)bal & 0xFFu;
        bool act_own = (actmask >> own) & 1u;

        // uniform per-beam prob tables (for parent values)
#define TBL(j) float pb8_##j = rlanef(pb_own, j); float pt8_##j = rlanef(pt_own, j);
        REP8(TBL)
#undef TBL

        // own parent match by node-id identity (ids content-faithful via dedup)
        int p_own = 0;
        bool matched = false;
        {
            bool gate = act_own && (len_own > 0);
#define PM(j)                                                                   \
            {                                                                   \
                bool m_ = gate && ((actmask >> j) & 1u) &&                      \
                          ((A8[j] >> 12) == par_own);                           \
                if (m_) { p_own = j; matched = true; }                          \
            }
            REP8(PM)
#undef PM
        }
        float pbp = pb8_0, ptp = pt8_0;
        int lastp = (int)(B8[0] & 127u);
#define PSEL(j)                                                                 \
        {                                                                       \
            bool m_ = (p_own == j);                                             \
            pbp = m_ ? pb8_##j : pbp;                                           \
            ptp = m_ ? pt8_##j : ptp;                                           \
            lastp = m_ ? (int)(B8[j] & 127u) : lastp;                           \
        }
        REP7(PSEL)
#undef PSEL
        float pprev = matched ? ((last_own == lastp) ? pbp : ptp) : LOG0f;
        float prLast = (last_own < 64) ? sfL : sfH;

        float contb_own = pt_own + prB;
        float contnb_own = (len_own > 0) ? (lae(pnb_own, pprev) + prLast) : LOG0f;
        float tot_own = lae(contb_own, contnb_own);

        // labels in my slice claimed as existing children of my beam
        unsigned claimed16 = 0;
#pragma unroll
        for (int j = 0; j < 8; ++j) {
            unsigned lastj = B8[j] & 127u;
            bool mj = ((actmask >> j) & 1u) && act_own && (node_own == (A8[j] & 0xFFFu));
            bool ins = ((lastj >> 4) == (unsigned)slice);
            claimed16 |= (mj && ins) ? (1u << (lastj & 15u)) : 0u;
        }

        // candidate value-words (named); full key = (kh, cl), cl: ext k -> KLB-k; cont -> ~own
        unsigned kh_0, kh_1, kh_2, kh_3, kh_4, kh_5, kh_6, kh_7, kh_8, kh_9,
                 kh_10, kh_11, kh_12, kh_13, kh_14, kh_15, kh_16;
#define MAKEK(c, pv)                                                                     \
        {                                                                                \
            int v = vbase + (c);                                                         \
            float prev = (v == last_own) ? pb_own : pt_own;                              \
            float val = (pv) + prev;                                                     \
            bool bad = (v == blank) | ((pv) <= PRUNE_TH) | (!act_own) |                  \
                       (bool)((claimed16 >> (c)) & 1u);                                  \
            if (bad) val = LOG0f;                                                        \
            kh_##c = mono(val);                                                          \
        }
        MAKEK(0, s0.x) MAKEK(1, s0.y) MAKEK(2, s0.z) MAKEK(3, s0.w)
        MAKEK(4, s1.x) MAKEK(5, s1.y) MAKEK(6, s1.z) MAKEK(7, s1.w)
        MAKEK(8, s2.x) MAKEK(9, s2.y) MAKEK(10, s2.z) MAKEK(11, s2.w)
        MAKEK(12, s3.x) MAKEK(13, s3.y) MAKEK(14, s3.z) MAKEK(15, s3.w)
#undef MAKEK
        kh_16 = (lane < 8) ? mono(tot_own) : 0u;

        // per-lane top-3 cache as (value, rank); rank 0=cont, k+1=ext slot k
        unsigned a1v = 0u, a1p = 31u, a2v = 0u, a2p = 31u, a3v = 0u, a3p = 31u;
        unsigned b1v = 0u, b1p = 31u, b2v = 0u, b2p = 31u, b3v = 0u, b3p = 31u;
#define CINS(c1v, c1p, c2v, c2p, c3v, c3p, V, PR)                               \
        {                                                                       \
            unsigned v_ = (V); bool g1 = v_ > c1v, g2 = v_ > c2v, g3 = v_ > c3v; \
            unsigned x1v = g1 ? v_ : c1v;  unsigned x1p = g1 ? (PR) : c1p;      \
            unsigned x2v = g1 ? c1v : (g2 ? v_ : c2v);                          \
            unsigned x2p = g1 ? c1p : (g2 ? (PR) : c2p);                        \
            c3v = (g1 | g2) ? c2v : (g3 ? v_ : c3v);                            \
            c3p = (g1 | g2) ? c2p : (g3 ? (PR) : c3p);                          \
            c1v = x1v; c1p = x1p; c2v = x2v; c2p = x2p;                         \
        }
        CINS(a1v, a1p, a2v, a2p, a3v, a3p, kh_16, 0u)
        CINS(a1v, a1p, a2v, a2p, a3v, a3p, kh_0, 1u)
        CINS(a1v, a1p, a2v, a2p, a3v, a3p, kh_2, 3u)
        CINS(a1v, a1p, a2v, a2p, a3v, a3p, kh_4, 5u)
        CINS(a1v, a1p, a2v, a2p, a3v, a3p, kh_6, 7u)
        CINS(a1v, a1p, a2v, a2p, a3v, a3p, kh_8, 9u)
        CINS(a1v, a1p, a2v, a2p, a3v, a3p, kh_10, 11u)
        CINS(a1v, a1p, a2v, a2p, a3v, a3p, kh_12, 13u)
        CINS(a1v, a1p, a2v, a2p, a3v, a3p, kh_14, 15u)
        CINS(b1v, b1p, b2v, b2p, b3v, b3p, kh_1, 2u)
        CINS(b1v, b1p, b2v, b2p, b3v, b3p, kh_3, 4u)
        CINS(b1v, b1p, b2v, b2p, b3v, b3p, kh_5, 6u)
        CINS(b1v, b1p, b2v, b2p, b3v, b3p, kh_7, 8u)
        CINS(b1v, b1p, b2v, b2p, b3v, b3p, kh_9, 10u)
        CINS(b1v, b1p, b2v, b2p, b3v, b3p, kh_11, 12u)
        CINS(b1v, b1p, b2v, b2p, b3v, b3p, kh_13, 14u)
        CINS(b1v, b1p, b2v, b2p, b3v, b3p, kh_15, 16u)
#undef CINS
#define GTE(xv, xp, yv, yp) (((xv) > (yv)) || ((xv) == (yv) && (xp) < (yp)))
        unsigned m1v, m1p, m2v, m2p, m3v, m3p;
        {
            bool gA = GTE(a1v, a1p, b1v, b1p);
            m1v = gA ? a1v : b1v; m1p = gA ? a1p : b1p;
            unsigned uv = gA ? b1v : a1v, up = gA ? b1p : a1p;   // leaders' loser
            bool gS = GTE(a2v, a2p, b2v, b2p);
            unsigned vv = gS ? a2v : b2v, vp = gS ? a2p : b2p;   // seconds' winner
            unsigned wv = gS ? b2v : a2v, wp = gS ? b2p : a2p;   // seconds' loser
            bool gM = GTE(uv, up, vv, vp);
            m2v = gM ? uv : vv; m2p = gM ? up : vp;
            unsigned mnv = gM ? vv : uv, mnp = gM ? vp : up;
            bool gX = GTE(a2v, a2p, b1v, b1p);
            bool gY = GTE(b2v, b2p, a1v, a1p);
            unsigned Xv = gX ? a3v : (gY ? b3v : 0u);
            unsigned Xp = gX ? a3p : (gY ? b3p : 31u);
            bool gW = GTE(wv, wp, Xv, Xp);
            unsigned Yv = gW ? wv : Xv, Yp = gW ? wp : Xp;
            bool gF = GTE(mnv, mnp, Yv, Yp);
            m3v = gF ? mnv : Yv; m3p = gF ? mnp : Yp;
        }
#undef GTE

        // continuation-value tables BEFORE rounds (latency hidden under rounds)
#define CBT(j) float cb8_##j = rlanef(contb_own, j); float cn8_##j = rlanef(contnb_own, j);
        REP8(CBT)
#undef CBT

        // top-8 extraction: submit-always, shift-on-win, refill on underflow
        unsigned selh_0, selh_1, selh_2, selh_3, selh_4, selh_5, selh_6, selh_7;
        unsigned sell_0, sell_1, sell_2, sell_3, sell_4, sell_5, sell_6, sell_7;
#define RS1(k)                                                                  \
        {                                                                       \
            unsigned kv = kh_##k; unsigned kcl = KLB - (unsigned)(k);           \
            bool below = (kv < M) | ((kv == M) & (kcl < L));                    \
            bool bet = below & ((kv > bv) | ((kv == bv) & (kcl > bcl)));        \
            bv = bet ? kv : bv; bp = bet ? (unsigned)((k) + 1) : bp;            \
            bcl = bet ? kcl : bcl;                                              \
        }
#define ROUND(r)                                                                \
        do {                                                                    \
            unsigned ch = m1v;                                                  \
            unsigned cl = (m1p == 0u) ? ~(unsigned)own : (KLB - (m1p - 1u));    \
            unsigned M = wred_max_u32(ch);                                      \
            unsigned long long tb = __ballot(ch == M);                          \
            unsigned L;                                                         \
            if (__builtin_popcountll(tb) == 1) {                                \
                L = rlaneu(cl, __builtin_ctzll(tb));                            \
            } else {                                                            \
                unsigned lo2 = (ch == M) ? cl : 0u;                             \
                L = wred_max_u32(lo2);                                          \
            }                                                                   \
            selh_##r = M; sell_##r = L;                                         \
            bool won = (ch == M) & (cl == L);                                   \
            m1v = won ? m2v : m1v; m1p = won ? m2p : m1p;                       \
            m2v = won ? m3v : m2v; m2p = won ? m3p : m2p;                       \
            m3v = won ? 0u : m3v;  m3p = won ? 31u : m3p;                       \
            bool under = won & (m1v == 0u);                                     \
            if (__any(under)) {                                                 \
                if (under) {  /* rescan: best key strictly below (M,L) */       \
                    unsigned bv = 0u, bp = 31u, bcl = 0u;                       \
                    RS1(0) RS1(1) RS1(2) RS1(3) RS1(4) RS1(5) RS1(6) RS1(7)     \
                    RS1(8) RS1(9) RS1(10) RS1(11) RS1(12) RS1(13) RS1(14)       \
                    RS1(15)                                                     \
                    {                                                           \
                        unsigned kv = kh_16; unsigned kcl = ~(unsigned)own;     \
                        bool below = (kv < M) | ((kv == M) & (kcl < L));        \
                        bool bet = below &                                      \
                                   ((kv > bv) | ((kv == bv) & (kcl > bcl)));    \
                        bv = bet ? kv : bv; bp = bet ? 0u : bp;                 \
                        bcl = bet ? kcl : bcl;                                  \
                    }                                                           \
                    m1v = bv; m1p = bp;  /* bv==0 -> lane exhausted */          \
                }                                                               \
            }                                                                   \
        } while (0);
        ROUND(0) ROUND(1) ROUND(2) ROUND(3) ROUND(4) ROUND(5) ROUND(6) ROUND(7)
#undef ROUND
#undef RS1

        // per-lane decode of round `own` (lanes 8..63 = replicas of beam own)
        unsigned myM, myL;
        SEL8N(myM, (unsigned)own, selh);
        SEL8N(myL, (unsigned)own, sell);
        unsigned sel = ~myL;
        bool iscont = sel < 8u;
        unsigned e = sel - 8u;
        unsigned s = iscont ? sel : (e >> 7);
        unsigned lab = e & 127u;
        unsigned Asel = sel8u(A8, s);
        unsigned Bsel = sel8u(B8, s);
        unsigned nd = Asel >> 12;
        unsigned ln = Bsel >> 7;
        float cbs, cns;
        {
            cbs = cb8_0; cns = cn8_0;
            cbs = (s == 1u) ? cb8_1 : cbs; cns = (s == 1u) ? cn8_1 : cns;
            cbs = (s == 2u) ? cb8_2 : cbs; cns = (s == 2u) ? cn8_2 : cns;
            cbs = (s == 3u) ? cb8_3 : cbs; cns = (s == 3u) ? cn8_3 : cns;
            cbs = (s == 4u) ? cb8_4 : cbs; cns = (s == 4u) ? cn8_4 : cns;
            cbs = (s == 5u) ? cb8_5 : cbs; cns = (s == 5u) ? cn8_5 : cns;
            cbs = (s == 6u) ? cb8_6 : cbs; cns = (s == 6u) ? cn8_6 : cns;
            cbs = (s == 7u) ? cb8_7 : cbs; cns = (s == 7u) ? cn8_7 : cns;
        }
        float npb_own = iscont ? cbs : LOG0f;
        float npnb_own = iscont ? cns : mono_inv(myM);  // ext pnb == sort value bitwise
        unsigned A_new = iscont ? Asel : nd;  // ext: node-field=0 (patched), par=nd
        unsigned B_new = iscont ? Bsel : (((ln + 1u) << 7) | lab);
        unsigned long long extbal = __ballot(!iscont);
        unsigned extmask = (unsigned)extbal & 0xFFu;  // bit r: round r was an extension

        // dedup-hash inserts: lane r handles new beam r (deterministic pre-ids)
        unsigned insRes = 0;
        if ((extmask >> lane) & 1u) {
            unsigned preid = 1u + 8u * (unsigned)t + (unsigned)lane;
            unsigned hkey = (nd << 7) | lab;
            unsigned entry = (hkey << 12) | preid;
            unsigned h = ((hkey * 2654435761u) >> 20) & HMASK;
            for (;;) {
                unsigned prev = atomicCAS(&hsh[h], HEMPTY, entry);
                if (prev == HEMPTY) { nodeinfo[preid] = hkey; insRes = preid; break; }
                if ((prev >> 12) == hkey) { insRes = prev & 0xFFFu; break; }
                h = (h + 1) & HMASK;
            }
        }
        // own-state directly from per-lane decode (+1 shfl for the node patch)
        unsigned patched = (unsigned)__shfl((int)insRes, own, 64);
        node_own = iscont ? (A_new >> 12) : patched;
        par_own = A_new & 0xFFFu;
        len_own = (int)(B_new >> 7);
        last_own = (int)(B_new & 127u);
        pb_own = npb_own; pnb_own = npnb_own;

        // commit uniform metadata: gather from lane r; patch ext node ids
#pragma unroll
        for (int r = 0; r < 8; ++r) {
            unsigned Ar = rlaneu(A_new, r);
            unsigned Br = rlaneu(B_new, r);
            if ((extmask >> r) & 1u)  // uniform condition
                Ar = (rlaneu(insRes, r) << 12) | (Ar & 0xFFFu);
            A8[r] = Ar; B8[r] = Br;
        }

        // rotate prefetch pipeline: cur <- nx <- q; prB <- mprB; new mprB from new nx
        s0 = m0; s1 = m1_; s2 = m2_; s3 = m3_;
        prL = mprL; prH = mprH;
        prB = mprB;
        m0 = q0; m1_ = q1; m2_ = q2; m3_ = q3;
        mprL = qprL; mprH = qprH;
        mprB = (blank < 64) ? rlanef(mprL, blank) : rlanef(mprH, blank - 64);
    }

    // final argmax of totals (ties -> lowest index), then parent-walk reconstruction
    unsigned fh, fl;
    {
        float tot = lae(pb_own, pnb_own);
        fh = (lane < 8) ? mono(tot) : 0u;
        fl = (lane < 8) ? ~(unsigned)lane : 0u;
    }
    {
        unsigned M = wred_max_u32(fh);
        unsigned lo2 = (fh == M) ? fl : 0u;
        fl = wred_max_u32(lo2);
    }
    const int best = (int)(~fl);
    int L = 0;
    unsigned c = 0;
#pragma unroll
    for (int j = 0; j < 8; ++j)
        if (best == j) { L = (int)(B8[j] >> 7); c = A8[j] >> 12; }
    if (lane == 0) {
        for (int k = L - 1; k >= 0; --k) {
            unsigned info = nodeinfo[c];
            sh_seq[k] = (int)(info & 127u);
            c = info >> 7;
        }
    }
    __syncthreads();
    for (int j = lane; j < T; j += 64)
        out_seq[(size_t)b * T + j] = (j < L) ? sh_seq[j] : 0;
    if (lane == 0) out_len[b] = L;
}

extern "C" void kernel_launch(void* const* d_in, const int* in_sizes, int n_in,
                              void* d_out, int out_size, void* d_ws, size_t ws_size,
                              hipStream_t stream) {
    const float* probs = (const float*)d_in[0];
    const int* lengths = (const int*)d_in[1];
    // d_in[2] = beam_width (fixed 8, compiled in); d_in[3] = blank_index
    const int* blank_p = (const int*)d_in[3];
    const int B = in_sizes[1];
    const int T = in_sizes[0] / (B * VCAB);
    int* out = (int*)d_out;
    ctc_beam_kernel<<<B, 64, 0, stream>>>(probs, lengths, blank_p, out,
                                          out + (size_t)B * T, T);
}

// Round 17
// 1125.790 us; speedup vs baseline: 1.0544x; 1.0041x over previous
//
#include <hip/hip_runtime.h>
#include <math.h>

#define LOG0f (-1.0e30f)
#define ACTIVE_TH (-1.0e29f)
#define PRUNE_TH (-9.0f)
#define VCAB 128
#define HSZ 4096
#define HMASK (HSZ - 1)
#define MAXN 2052
#define HEMPTY 0xFFFFFFFFu

// JAX-exact logaddexp: max + log1p(exp(-|a-b|)) in f32
__device__ __forceinline__ float lae(float a, float b) {
    float mx = fmaxf(a, b);
    float d = fabsf(a - b);
    return mx + log1pf(expf(-d));
}
// monotonic float->uint transform (order-preserving; >0 for all finite floats)
__device__ __forceinline__ unsigned mono(float f) {
    unsigned u = __float_as_uint(f);
    return (u & 0x80000000u) ? ~u : (u | 0x80000000u);
}
__device__ __forceinline__ float mono_inv(unsigned m) {
    unsigned u = (m & 0x80000000u) ? (m & 0x7FFFFFFFu) : ~m;
    return __uint_as_float(u);
}
__device__ __forceinline__ unsigned rlaneu(unsigned x, int l) {
    return (unsigned)__builtin_amdgcn_readlane((int)x, l);
}
__device__ __forceinline__ float rlanef(float x, int l) {
    return __uint_as_float(rlaneu(__float_as_uint(x), l));
}
// select a[s] from a statically-indexed 8-array (cndmask chain)
__device__ __forceinline__ unsigned sel8u(const unsigned a[8], unsigned s) {
    unsigned r = a[0];
#pragma unroll
    for (int j = 1; j < 8; ++j) r = (s == (unsigned)j) ? a[j] : r;
    return r;
}

// wave-wide max of u32, SPLIT form: 4 DPP row-max levels (row max lands in
// lanes 15/31/47/63) + 4 parallel readlanes + depth-2 scalar max tree.
__device__ __forceinline__ unsigned wred_max_u32(unsigned x) {
    unsigned y;
    y = (unsigned)__builtin_amdgcn_update_dpp(0, (int)x, 0x111, 0xf, 0xf, false);  // row_shr:1
    x = (y > x) ? y : x;
    y = (unsigned)__builtin_amdgcn_update_dpp(0, (int)x, 0x112, 0xf, 0xf, false);  // row_shr:2
    x = (y > x) ? y : x;
    y = (unsigned)__builtin_amdgcn_update_dpp(0, (int)x, 0x114, 0xf, 0xf, false);  // row_shr:4
    x = (y > x) ? y : x;
    y = (unsigned)__builtin_amdgcn_update_dpp(0, (int)x, 0x118, 0xf, 0xf, false);  // row_shr:8
    x = (y > x) ? y : x;  // lane 15 of each 16-row now holds that row's max
    unsigned r0 = rlaneu(x, 15);
    unsigned r1 = rlaneu(x, 31);
    unsigned r2 = rlaneu(x, 47);
    unsigned r3 = rlaneu(x, 63);
    unsigned m01 = (r0 > r1) ? r0 : r1;
    unsigned m23 = (r2 > r3) ? r2 : r3;
    return (m01 > m23) ? m01 : m23;
}

#define REP8(X) X(0) X(1) X(2) X(3) X(4) X(5) X(6) X(7)
#define REP7(X) X(1) X(2) X(3) X(4) X(5) X(6) X(7)
#define SEL8N(out, s, n)                                                        \
    do {                                                                        \
        out = n##_0;                                                            \
        out = ((s) == 1u) ? n##_1 : out; out = ((s) == 2u) ? n##_2 : out;       \
        out = ((s) == 3u) ? n##_3 : out; out = ((s) == 4u) ? n##_4 : out;       \
        out = ((s) == 5u) ? n##_5 : out; out = ((s) == 6u) ? n##_6 : out;       \
        out = ((s) == 7u) ? n##_7 : out;                                        \
    } while (0)

__global__ __launch_bounds__(64)
void ctc_beam_kernel(const float* __restrict__ probs, const int* __restrict__ lengths,
                     const int* __restrict__ blank_p, int* __restrict__ out_seq,
                     int* __restrict__ out_len, int T) {
    __shared__ unsigned hsh[HSZ];        // dedup map (parent,label)->node: (hkey<<12)|id
    __shared__ unsigned nodeinfo[MAXN];  // (parent<<7)|label per node id
    __shared__ int sh_seq[256];

    const int lane = threadIdx.x;
    const int b = blockIdx.x;
    const int blank = blank_p[0];
    const int length = lengths[b];
    const float* __restrict__ P = probs + (size_t)b * T * VCAB;
    const float4* __restrict__ P4 = (const float4*)P;
    const int own = lane & 7;     // beam owned by this lane
    const int slice = lane >> 3;  // vocab slice [slice*16, +16)
    const int vbase = slice * 16;
    // ext tie-break word for slot k: cl = KLB - k  (== ~refidx); cont: ~own
    const unsigned KLB = ~(8u + (unsigned)(own * VCAB + vbase));

    for (int i = lane; i < HSZ; i += 64) hsh[i] = HEMPTY;
    __syncthreads();

    // packed wave-uniform metadata: A8[j]=(node<<12)|par, B8[j]=(len<<7)|last
    unsigned A8[8], B8[8];
#pragma unroll
    for (int j = 0; j < 8; ++j) { A8[j] = 0xFFFu; B8[j] = (unsigned)blank; }
    // per-lane own-beam state (lane j authoritative for beam j; others replicas)
    float pb_own = (own == 0) ? 0.0f : LOG0f;  // root: blank prob = log(1)
    float pnb_own = LOG0f;
    int len_own = 0, last_own = blank;
    unsigned node_own = 0, par_own = 0xFFFu;

    // distance-2 prefetch: s* = row t, m* = row t+1; prB pipelined one step early
    float4 s0, s1, s2, s3, m0, m1_, m2_, m3_;
    float prL, prH, mprL, mprH, prB, mprB;
    {
        int base4 = (vbase >> 2);
        s0 = P4[base4]; s1 = P4[base4 + 1]; s2 = P4[base4 + 2]; s3 = P4[base4 + 3];
        prL = P[lane]; prH = P[64 + lane];
        int t1 = (1 < length) ? 1 : 0;
        int b1 = t1 * 32 + (vbase >> 2);
        m0 = P4[b1]; m1_ = P4[b1 + 1]; m2_ = P4[b1 + 2]; m3_ = P4[b1 + 3];
        mprL = P[(size_t)t1 * VCAB + lane];
        mprH = P[(size_t)t1 * VCAB + 64 + lane];
        prB = (blank < 64) ? rlanef(prL, blank) : rlanef(prH, blank - 64);
        mprB = (blank < 64) ? rlanef(mprL, blank) : rlanef(mprH, blank - 64);
    }

#pragma clang loop unroll(disable)
    for (int t = 0; t < length; ++t) {
        // early cross-lane issue: row prob at own's last label (latency hidden below)
        float sfL = __shfl(prL, last_own & 63, 64);
        float sfH = __shfl(prH, last_own & 63, 64);
        // issue loads for row t+2 (clamped)
        const int t2 = (t + 2 < length) ? (t + 2) : (length - 1);
        float4 q0, q1, q2, q3;
        float qprL, qprH;
        {
            int base4 = t2 * 32 + (vbase >> 2);
            q0 = P4[base4]; q1 = P4[base4 + 1]; q2 = P4[base4 + 2]; q3 = P4[base4 + 3];
            qprL = P[(size_t)t2 * VCAB + lane];
            qprH = P[(size_t)t2 * VCAB + 64 + lane];
        }

        float pt_own = lae(pb_own, pnb_own);
        unsigned long long bal = __ballot(pt_own > ACTIVE_TH);
        unsigned actmask = (unsigned)bal & 0xFFu;
        bool act_own = (actmask >> own) & 1u;

        // uniform per-beam prob tables (for parent values)
#define TBL(j) float pb8_##j = rlanef(pb_own, j); float pt8_##j = rlanef(pt_own, j);
        REP8(TBL)
#undef TBL

        // own parent match by node-id identity (ids content-faithful via dedup)
        int p_own = 0;
        bool matched = false;
        {
            bool gate = act_own && (len_own > 0);
#define PM(j)                                                                   \
            {                                                                   \
                bool m_ = gate && ((actmask >> j) & 1u) &&                      \
                          ((A8[j] >> 12) == par_own);                           \
                if (m_) { p_own = j; matched = true; }                          \
            }
            REP8(PM)
#undef PM
        }
        float pbp = pb8_0, ptp = pt8_0;
        int lastp = (int)(B8[0] & 127u);
#define PSEL(j)                                                                 \
        {                                                                       \
            bool m_ = (p_own == j);                                             \
            pbp = m_ ? pb8_##j : pbp;                                           \
            ptp = m_ ? pt8_##j : ptp;                                           \
            lastp = m_ ? (int)(B8[j] & 127u) : lastp;                           \
        }
        REP7(PSEL)
#undef PSEL
        float pprev = matched ? ((last_own == lastp) ? pbp : ptp) : LOG0f;
        float prLast = (last_own < 64) ? sfL : sfH;

        float contb_own = pt_own + prB;
        float contnb_own = (len_own > 0) ? (lae(pnb_own, pprev) + prLast) : LOG0f;
        float tot_own = lae(contb_own, contnb_own);

        // labels in my slice claimed as existing children of my beam
        unsigned claimed16 = 0;
#pragma unroll
        for (int j = 0; j < 8; ++j) {
            unsigned lastj = B8[j] & 127u;
            bool mj = ((actmask >> j) & 1u) && act_own && (node_own == (A8[j] & 0xFFFu));
            bool ins = ((lastj >> 4) == (unsigned)slice);
            claimed16 |= (mj && ins) ? (1u << (lastj & 15u)) : 0u;
        }

        // candidate value-words (named); full key = (kh, cl), cl: ext k -> KLB-k; cont -> ~own
        unsigned kh_0, kh_1, kh_2, kh_3, kh_4, kh_5, kh_6, kh_7, kh_8, kh_9,
                 kh_10, kh_11, kh_12, kh_13, kh_14, kh_15, kh_16;
#define MAKEK(c, pv)                                                                     \
        {                                                                                \
            int v = vbase + (c);                                                         \
            float prev = (v == last_own) ? pb_own : pt_own;                              \
            float val = (pv) + prev;                                                     \
            bool bad = (v == blank) | ((pv) <= PRUNE_TH) | (!act_own) |                  \
                       (bool)((claimed16 >> (c)) & 1u);                                  \
            if (bad) val = LOG0f;                                                        \
            kh_##c = mono(val);                                                          \
        }
        MAKEK(0, s0.x) MAKEK(1, s0.y) MAKEK(2, s0.z) MAKEK(3, s0.w)
        MAKEK(4, s1.x) MAKEK(5, s1.y) MAKEK(6, s1.z) MAKEK(7, s1.w)
        MAKEK(8, s2.x) MAKEK(9, s2.y) MAKEK(10, s2.z) MAKEK(11, s2.w)
        MAKEK(12, s3.x) MAKEK(13, s3.y) MAKEK(14, s3.z) MAKEK(15, s3.w)
#undef MAKEK
        kh_16 = (lane < 8) ? mono(tot_own) : 0u;

        // per-lane top-3 cache as (value, rank); rank 0=cont, k+1=ext slot k.
        // EXT-ONLY insert chains (run in parallel with the lae2/lae3 chain);
        // cont key merged at the end as a rank-aware singleton.
        unsigned a1v = 0u, a1p = 31u, a2v = 0u, a2p = 31u, a3v = 0u, a3p = 31u;
        unsigned b1v = 0u, b1p = 31u, b2v = 0u, b2p = 31u, b3v = 0u, b3p = 31u;
#define CINS(c1v, c1p, c2v, c2p, c3v, c3p, V, PR)                               \
        {                                                                       \
            unsigned v_ = (V); bool g1 = v_ > c1v, g2 = v_ > c2v, g3 = v_ > c3v; \
            unsigned x1v = g1 ? v_ : c1v;  unsigned x1p = g1 ? (PR) : c1p;      \
            unsigned x2v = g1 ? c1v : (g2 ? v_ : c2v);                          \
            unsigned x2p = g1 ? c1p : (g2 ? (PR) : c2p);                        \
            c3v = (g1 | g2) ? c2v : (g3 ? v_ : c3v);                            \
            c3p = (g1 | g2) ? c2p : (g3 ? (PR) : c3p);                          \
            c1v = x1v; c1p = x1p; c2v = x2v; c2p = x2p;                         \
        }
        CINS(a1v, a1p, a2v, a2p, a3v, a3p, kh_0, 1u)
        CINS(a1v, a1p, a2v, a2p, a3v, a3p, kh_2, 3u)
        CINS(a1v, a1p, a2v, a2p, a3v, a3p, kh_4, 5u)
        CINS(a1v, a1p, a2v, a2p, a3v, a3p, kh_6, 7u)
        CINS(a1v, a1p, a2v, a2p, a3v, a3p, kh_8, 9u)
        CINS(a1v, a1p, a2v, a2p, a3v, a3p, kh_10, 11u)
        CINS(a1v, a1p, a2v, a2p, a3v, a3p, kh_12, 13u)
        CINS(a1v, a1p, a2v, a2p, a3v, a3p, kh_14, 15u)
        CINS(b1v, b1p, b2v, b2p, b3v, b3p, kh_1, 2u)
        CINS(b1v, b1p, b2v, b2p, b3v, b3p, kh_3, 4u)
        CINS(b1v, b1p, b2v, b2p, b3v, b3p, kh_5, 6u)
        CINS(b1v, b1p, b2v, b2p, b3v, b3p, kh_7, 8u)
        CINS(b1v, b1p, b2v, b2p, b3v, b3p, kh_9, 10u)
        CINS(b1v, b1p, b2v, b2p, b3v, b3p, kh_11, 12u)
        CINS(b1v, b1p, b2v, b2p, b3v, b3p, kh_13, 14u)
        CINS(b1v, b1p, b2v, b2p, b3v, b3p, kh_15, 16u)
#undef CINS
#define GTE(xv, xp, yv, yp) (((xv) > (yv)) || ((xv) == (yv) && (xp) < (yp)))
        // exact merge of the two ext top-3 chains
        unsigned p1v, p1p, p2v, p2p, p3v, p3p;
        {
            bool gA = GTE(a1v, a1p, b1v, b1p);
            p1v = gA ? a1v : b1v; p1p = gA ? a1p : b1p;
            unsigned uv = gA ? b1v : a1v, up = gA ? b1p : a1p;   // leaders' loser
            bool gS = GTE(a2v, a2p, b2v, b2p);
            unsigned vv = gS ? a2v : b2v, vp = gS ? a2p : b2p;   // seconds' winner
            unsigned wv = gS ? b2v : a2v, wp = gS ? b2p : a2p;   // seconds' loser
            bool gM = GTE(uv, up, vv, vp);
            p2v = gM ? uv : vv; p2p = gM ? up : vp;
            unsigned mnv = gM ? vv : uv, mnp = gM ? vp : up;
            bool gX = GTE(a2v, a2p, b1v, b1p);
            bool gY = GTE(b2v, b2p, a1v, a1p);
            unsigned Xv = gX ? a3v : (gY ? b3v : 0u);
            unsigned Xp = gX ? a3p : (gY ? b3p : 31u);
            bool gW = GTE(wv, wp, Xv, Xp);
            unsigned Yv = gW ? wv : Xv, Yp = gW ? wp : Xp;
            bool gF = GTE(mnv, mnp, Yv, Yp);
            p3v = gF ? mnv : Yv; p3p = gF ? mnp : Yp;
        }
        // singleton merge: cont key (kh_16, rank 0) into (p1,p2,p3)
        unsigned m1v, m1p, m2v, m2p, m3v, m3p;
        {
            unsigned sv = kh_16;
            bool gs1 = GTE(sv, 0u, p1v, p1p);
            bool gs2 = GTE(sv, 0u, p2v, p2p);
            bool gs3 = GTE(sv, 0u, p3v, p3p);
            m1v = gs1 ? sv : p1v;  m1p = gs1 ? 0u : p1p;
            m2v = gs1 ? p1v : (gs2 ? sv : p2v);
            m2p = gs1 ? p1p : (gs2 ? 0u : p2p);
            m3v = gs2 ? p2v : (gs3 ? sv : p3v);
            m3p = gs2 ? p2p : (gs3 ? 0u : p3p);
        }
#undef GTE

        // continuation-value tables BEFORE rounds (latency hidden under rounds)
#define CBT(j) float cb8_##j = rlanef(contb_own, j); float cn8_##j = rlanef(contnb_own, j);
        REP8(CBT)
#undef CBT

        // top-8 extraction: submit-always, shift-on-win, refill on underflow
        unsigned selh_0, selh_1, selh_2, selh_3, selh_4, selh_5, selh_6, selh_7;
        unsigned sell_0, sell_1, sell_2, sell_3, sell_4, sell_5, sell_6, sell_7;
#define RS1(k)                                                                  \
        {                                                                       \
            unsigned kv = kh_##k; unsigned kcl = KLB - (unsigned)(k);           \
            bool below = (kv < M) | ((kv == M) & (kcl < L));                    \
            bool bet = below & ((kv > bv) | ((kv == bv) & (kcl > bcl)));        \
            bv = bet ? kv : bv; bp = bet ? (unsigned)((k) + 1) : bp;            \
            bcl = bet ? kcl : bcl;                                              \
        }
#define ROUND(r)                                                                \
        do {                                                                    \
            unsigned ch = m1v;                                                  \
            unsigned cl = (m1p == 0u) ? ~(unsigned)own : (KLB - (m1p - 1u));    \
            unsigned M = wred_max_u32(ch);                                      \
            unsigned long long tb = __ballot(ch == M);                          \
            unsigned L;                                                         \
            if (__builtin_popcountll(tb) == 1) {                                \
                L = rlaneu(cl, __builtin_ctzll(tb));                            \
            } else {                                                            \
                unsigned lo2 = (ch == M) ? cl : 0u;                             \
                L = wred_max_u32(lo2);                                          \
            }                                                                   \
            selh_##r = M; sell_##r = L;                                         \
            bool won = (ch == M) & (cl == L);                                   \
            m1v = won ? m2v : m1v; m1p = won ? m2p : m1p;                       \
            m2v = won ? m3v : m2v; m2p = won ? m3p : m2p;                       \
            m3v = won ? 0u : m3v;  m3p = won ? 31u : m3p;                       \
            bool under = won & (m1v == 0u);                                     \
            if (__any(under)) {                                                 \
                if (under) {  /* rescan: best key strictly below (M,L) */       \
                    unsigned bv = 0u, bp = 31u, bcl = 0u;                       \
                    RS1(0) RS1(1) RS1(2) RS1(3) RS1(4) RS1(5) RS1(6) RS1(7)     \
                    RS1(8) RS1(9) RS1(10) RS1(11) RS1(12) RS1(13) RS1(14)       \
                    RS1(15)                                                     \
                    {                                                           \
                        unsigned kv = kh_16; unsigned kcl = ~(unsigned)own;     \
                        bool below = (kv < M) | ((kv == M) & (kcl < L));        \
                        bool bet = below &                                      \
                                   ((kv > bv) | ((kv == bv) & (kcl > bcl)));    \
                        bv = bet ? kv : bv; bp = bet ? 0u : bp;                 \
                        bcl = bet ? kcl : bcl;                                  \
                    }                                                           \
                    m1v = bv; m1p = bp;  /* bv==0 -> lane exhausted */          \
                }                                                               \
            }                                                                   \
        } while (0);
        ROUND(0) ROUND(1) ROUND(2) ROUND(3) ROUND(4) ROUND(5) ROUND(6) ROUND(7)
#undef ROUND
#undef RS1

        // per-lane decode of round `own` (lanes 8..63 = replicas of beam own)
        unsigned myM, myL;
        SEL8N(myM, (unsigned)own, selh);
        SEL8N(myL, (unsigned)own, sell);
        unsigned sel = ~myL;
        bool iscont = sel < 8u;
        unsigned e = sel - 8u;
        unsigned s = iscont ? sel : (e >> 7);
        unsigned lab = e & 127u;
        unsigned Asel = sel8u(A8, s);
        unsigned Bsel = sel8u(B8, s);
        unsigned nd = Asel >> 12;
        unsigned ln = Bsel >> 7;
        float cbs, cns;
        {
            cbs = cb8_0; cns = cn8_0;
            cbs = (s == 1u) ? cb8_1 : cbs; cns = (s == 1u) ? cn8_1 : cns;
            cbs = (s == 2u) ? cb8_2 : cbs; cns = (s == 2u) ? cn8_2 : cns;
            cbs = (s == 3u) ? cb8_3 : cbs; cns = (s == 3u) ? cn8_3 : cns;
            cbs = (s == 4u) ? cb8_4 : cbs; cns = (s == 4u) ? cn8_4 : cns;
            cbs = (s == 5u) ? cb8_5 : cbs; cns = (s == 5u) ? cn8_5 : cns;
            cbs = (s == 6u) ? cb8_6 : cbs; cns = (s == 6u) ? cn8_6 : cns;
            cbs = (s == 7u) ? cb8_7 : cbs; cns = (s == 7u) ? cn8_7 : cns;
        }
        float npb_own = iscont ? cbs : LOG0f;
        float npnb_own = iscont ? cns : mono_inv(myM);  // ext pnb == sort value bitwise
        unsigned A_new = iscont ? Asel : nd;  // ext: node-field=0 (patched), par=nd
        unsigned B_new = iscont ? Bsel : (((ln + 1u) << 7) | lab);
        unsigned long long extbal = __ballot(!iscont);
        unsigned extmask = (unsigned)extbal & 0xFFu;  // bit r: round r was an extension

        // dedup-hash inserts: lane r handles new beam r (deterministic pre-ids)
        unsigned insRes = 0;
        if ((extmask >> lane) & 1u) {
            unsigned preid = 1u + 8u * (unsigned)t + (unsigned)lane;
            unsigned hkey = (nd << 7) | lab;
            unsigned entry = (hkey << 12) | preid;
            unsigned h = ((hkey * 2654435761u) >> 20) & HMASK;
            for (;;) {
                unsigned prev = atomicCAS(&hsh[h], HEMPTY, entry);
                if (prev == HEMPTY) { nodeinfo[preid] = hkey; insRes = preid; break; }
                if ((prev >> 12) == hkey) { insRes = prev & 0xFFFu; break; }
                h = (h + 1) & HMASK;
            }
        }
        // own-state directly from per-lane decode (+1 shfl for the node patch)
        unsigned patched = (unsigned)__shfl((int)insRes, own, 64);
        node_own = iscont ? (A_new >> 12) : patched;
        par_own = A_new & 0xFFFu;
        len_own = (int)(B_new >> 7);
        last_own = (int)(B_new & 127u);
        pb_own = npb_own; pnb_own = npnb_own;

        // commit uniform metadata: gather from lane r; patch ext node ids
#pragma unroll
        for (int r = 0; r < 8; ++r) {
            unsigned Ar = rlaneu(A_new, r);
            unsigned Br = rlaneu(B_new, r);
            if ((extmask >> r) & 1u)  // uniform condition
                Ar = (rlaneu(insRes, r) << 12) | (Ar & 0xFFFu);
            A8[r] = Ar; B8[r] = Br;
        }

        // rotate prefetch pipeline: cur <- nx <- q; prB <- mprB; new mprB from new nx
        s0 = m0; s1 = m1_; s2 = m2_; s3 = m3_;
        prL = mprL; prH = mprH;
        prB = mprB;
        m0 = q0; m1_ = q1; m2_ = q2; m3_ = q3;
        mprL = qprL; mprH = qprH;
        mprB = (blank < 64) ? rlanef(mprL, blank) : rlanef(mprH, blank - 64);
    }

    // final argmax of totals (ties -> lowest index), then parent-walk reconstruction
    unsigned fh, fl;
    {
        float tot = lae(pb_own, pnb_own);
        fh = (lane < 8) ? mono(tot) : 0u;
        fl = (lane < 8) ? ~(unsigned)lane : 0u;
    }
    {
        unsigned M = wred_max_u32(fh);
        unsigned lo2 = (fh == M) ? fl : 0u;
        fl = wred_max_u32(lo2);
    }
    const int best = (int)(~fl);
    int L = 0;
    unsigned c = 0;
#pragma unroll
    for (int j = 0; j < 8; ++j)
        if (best == j) { L = (int)(B8[j] >> 7); c = A8[j] >> 12; }
    if (lane == 0) {
        for (int k = L - 1; k >= 0; --k) {
            unsigned info = nodeinfo[c];
            sh_seq[k] = (int)(info & 127u);
            c = info >> 7;
        }
    }
    __syncthreads();
    for (int j = lane; j < T; j += 64)
        out_seq[(size_t)b * T + j] = (j < L) ? sh_seq[j] : 0;
    if (lane == 0) out_len[b] = L;
}

extern "C" void kernel_launch(void* const* d_in, const int* in_sizes, int n_in,
                              void* d_out, int out_size, void* d_ws, size_t ws_size,
                              hipStream_t stream) {
    const float* probs = (const float*)d_in[0];
    const int* lengths = (const int*)d_in[1];
    // d_in[2] = beam_width (fixed 8, compiled in); d_in[3] = blank_index
    const int* blank_p = (const int*)d_in[3];
    const int B = in_sizes[1];
    const int T = in_sizes[0] / (B * VCAB);
    int* out = (int*)d_out;
    ctc_beam_kernel<<<B, 64, 0, stream>>>(probs, lengths, blank_p, out,
                                          out + (size_t)B * T, T);
}